// Round 10
// baseline (913.397 us; speedup 1.0000x reference)
//
#include <hip/hip_runtime.h>

#define HID 128   // feature width (D == H == 128)

// ---------------- bf16 helpers ----------------
__device__ __forceinline__ float bf2f(unsigned short u) {
    union { unsigned int i; float f; } v;
    v.i = ((unsigned int)u) << 16;
    return v.f;
}
__device__ __forceinline__ unsigned short f2bf(float f) {
    union { float f; unsigned int i; } v;
    v.f = f;
    unsigned int lsb = (v.i >> 16) & 1u;
    v.i += 0x7fffu + lsb;   // round-to-nearest-even
    return (unsigned short)(v.i >> 16);
}

typedef __attribute__((ext_vector_type(8))) short bf16x8;   // 8 bf16 (4 VGPRs)
typedef __attribute__((ext_vector_type(4))) float f32x4;    // MFMA acc

// ---------------- preprocessing ----------------
__global__ void k_deg(const int* __restrict__ col, int* __restrict__ degI, int E) {
    int i = blockIdx.x * blockDim.x + threadIdx.x;
    if (i < E) atomicAdd(&degI[col[i]], 1);
}

// ---- 3-phase device-wide exclusive scan of (degI[i]+1) -> indptr, cursor ----
__global__ void k_scan_part(const int* __restrict__ degI, int* __restrict__ partial,
                            int* __restrict__ sums, int N) {
    __shared__ int sh[1024];
    int tid = threadIdx.x;
    int i = blockIdx.x * 1024 + tid;
    int v = (i < N) ? (degI[i] + 1) : 0;
    sh[tid] = v;
    __syncthreads();
    for (int off = 1; off < 1024; off <<= 1) {
        int t = (tid >= off) ? sh[tid - off] : 0;
        __syncthreads();
        sh[tid] += t;
        __syncthreads();
    }
    if (i < N) partial[i] = sh[tid] - v;
    if (tid == 1023) sums[blockIdx.x] = sh[1023];
}
__global__ void k_scan_tops(int* __restrict__ sums, int* __restrict__ indptr,
                            int nblocks, int N) {
    __shared__ int sh[1024];
    int tid = threadIdx.x;
    int v = (tid < nblocks) ? sums[tid] : 0;
    sh[tid] = v;
    __syncthreads();
    for (int off = 1; off < 1024; off <<= 1) {
        int t = (tid >= off) ? sh[tid - off] : 0;
        __syncthreads();
        sh[tid] += t;
        __syncthreads();
    }
    if (tid < nblocks) sums[tid] = sh[tid] - v;   // exclusive
    if (tid == 1023) indptr[N] = sh[1023];        // grand total = E + N
}
// phase 3: emit indptr + cursor + dinv = 1/sqrt(deg+1)
__global__ void k_scan_fix(const int* __restrict__ partial, const int* __restrict__ sums,
                           const int* __restrict__ degI, int* __restrict__ indptr,
                           int* __restrict__ cursor, float* __restrict__ dinv, int N) {
    int i = blockIdx.x * blockDim.x + threadIdx.x;
    if (i < N) {
        int ex = partial[i] + sums[i >> 10];
        indptr[i] = ex;
        cursor[i] = ex;
        dinv[i] = 1.0f / sqrtf((float)(degI[i] + 1));
    }
}

// batch is SORTED -> graph segment bounds via binary search
__global__ void k_gbounds(const int* __restrict__ batch, int* __restrict__ gstart,
                          int N, int G) {
    int g = blockIdx.x * blockDim.x + threadIdx.x;
    if (g > G) return;
    int lo = 0, hi = N;
    while (lo < hi) {
        int mid = (lo + hi) >> 1;
        if (batch[mid] < g) lo = mid + 1; else hi = mid;
    }
    gstart[g] = lo;
}

// ---- pre-swizzle W1..W4 (f32, k-major) into B-fragment-ordered bf16 ----
// B fragment layout: lane(q=lane>>4,c=lane&15) holds B[k=q*8+j][n], fragment
// for (ks,ct) starts at (((ks*8+ct)*4+q)*16+c)*8. Done ONCE; GEMM blocks then
// read fragments straight from L2 (no per-block LDS staging / conversion).
__global__ void k_wprep(const float* __restrict__ W1, const float* __restrict__ W2,
                        const float* __restrict__ W3, const float* __restrict__ W4,
                        unsigned short* __restrict__ Wg) {
    int m = blockIdx.x >> 6;                       // matrix index 0..3
    int i = (blockIdx.x & 63) * 256 + threadIdx.x; // element 0..16383
    const float* Wm = (m == 0) ? W1 : (m == 1) ? W2 : (m == 2) ? W3 : W4;
    int k = i >> 7, n = i & 127;
    int ks = k >> 5, q = (k >> 3) & 3, j = k & 7;
    int ct = n >> 4, c = n & 15;
    Wg[m * 16384 + ((((ks * 8 + ct) * 4 + q) * 16 + c) << 3) + j] = f2bf(Wm[i]);
}

// ---------------- MFMA GEMM body (no LDS; B fragments from L2) ---------------
// Output scaled by dinv[row]: buf0 holds t' = (A@W) * dinv_row, so the CSR
// needs only src indices (h[d] = dinv[d] * sum t'[s]  -- GCN factorization).
__device__ __forceinline__ bf16x8 a_frag_load(const unsigned short* p) {
    return *(const bf16x8*)p;
}
__device__ __forceinline__ bf16x8 a_frag_load(const float* p) {
    bf16x8 r;
#pragma unroll
    for (int i = 0; i < 8; ++i) r[i] = (short)f2bf(p[i]);
    return r;
}

template <typename TA>
__device__ __forceinline__ void gemm_body(const TA* __restrict__ A,
                                          const unsigned short* __restrict__ Wg,
                                          const float* __restrict__ dinv,
                                          unsigned short* __restrict__ C,
                                          int N, int blk) {
    const int tid = threadIdx.x;
    const int lane = tid & 63, wave = tid >> 6;
    const int q = lane >> 4, c = lane & 15;
    const int rowBase = blk * 128 + wave * 32;

    f32x4 acc[2][8];
#pragma unroll
    for (int rt = 0; rt < 2; ++rt)
#pragma unroll
        for (int ct = 0; ct < 8; ++ct)
            acc[rt][ct] = (f32x4){0.f, 0.f, 0.f, 0.f};

    const bf16x8 zfrag = {};
#pragma unroll
    for (int ks = 0; ks < 4; ++ks) {
        bf16x8 a[2];
#pragma unroll
        for (int rt = 0; rt < 2; ++rt) {
            int r = rowBase + rt * 16 + c;
            a[rt] = (r < N) ? a_frag_load(A + (size_t)r * HID + ks * 32 + q * 8)
                            : zfrag;
        }
#pragma unroll
        for (int ct = 0; ct < 8; ++ct) {
            bf16x8 b = *(const bf16x8*)&Wg[((((ks * 8 + ct) * 4 + q) * 16 + c) << 3)];
            acc[0][ct] = __builtin_amdgcn_mfma_f32_16x16x32_bf16(a[0], b, acc[0][ct], 0, 0, 0);
            acc[1][ct] = __builtin_amdgcn_mfma_f32_16x16x32_bf16(a[1], b, acc[1][ct], 0, 0, 0);
        }
    }
#pragma unroll
    for (int rt = 0; rt < 2; ++rt)
#pragma unroll
        for (int reg = 0; reg < 4; ++reg) {
            int r = rowBase + rt * 16 + q * 4 + reg;
            if (r < N) {
                float s = dinv[r];
#pragma unroll
                for (int ct = 0; ct < 8; ++ct)
                    C[(size_t)r * HID + ct * 16 + c] = f2bf(acc[rt][ct][reg] * s);
            }
        }
}

// fat kernel: layer-0 GEMM + flat CSR scatter (4B src-only entries)
__global__ __launch_bounds__(256) void k_fused0(const float* __restrict__ x,
                                                const unsigned short* __restrict__ Wg,
                                                const float* __restrict__ dinv,
                                                unsigned short* __restrict__ buf0,
                                                const int* __restrict__ row,
                                                const int* __restrict__ col,
                                                int* __restrict__ cursor,
                                                int* __restrict__ adjs,
                                                int E, int N, int gemmGrid) {
    if (blockIdx.x < gemmGrid) {
        gemm_body<float>(x, Wg, dinv, buf0, N, blockIdx.x);
        return;
    }
    int e = (blockIdx.x - gemmGrid) * blockDim.x + threadIdx.x;
    if (e >= E + N) return;
    int s, d;
    if (e < E) { s = row[e]; d = col[e]; }
    else       { s = d = e - E; }          // self loop
    int p = atomicAdd(&cursor[d], 1);
    adjs[p] = s;                            // 4B store (norm folded into t'/epilogue)
}

// layers 1..4 GEMM (A is bf16)
__global__ __launch_bounds__(256) void k_gemm_mfma(const unsigned short* __restrict__ A,
                                                   const unsigned short* __restrict__ Wg,
                                                   const float* __restrict__ dinv,
                                                   unsigned short* __restrict__ C,
                                                   int N) {
    gemm_body<unsigned short>(A, Wg, dinv, C, N, blockIdx.x);
}

// ---------------- CSR gather-aggregate + dinv[d]*sum + bias + ReLU -----------
__global__ __launch_bounds__(256) void k_aggregate(const unsigned short* __restrict__ t,
                                                   const int* __restrict__ indptr,
                                                   const int* __restrict__ adjs,
                                                   const float* __restrict__ dinv,
                                                   const float* __restrict__ bias,
                                                   unsigned short* __restrict__ h, int N) {
    int node = blockIdx.x * 4 + (threadIdx.x >> 6);
    if (node >= N) return;
    int lane = threadIdx.x & 63;
    int s = indptr[node], e = indptr[node + 1];
    float ax[4] = {0.f, 0.f, 0.f, 0.f};
    float ay[4] = {0.f, 0.f, 0.f, 0.f};
    int p = s;
    for (; p + 7 < e; p += 8) {
        unsigned int v[8];
#pragma unroll
        for (int u = 0; u < 8; ++u) {
            int ss = adjs[p + u];
            v[u] = ((const unsigned int*)(t + (size_t)ss * HID))[lane];
        }
#pragma unroll
        for (int u = 0; u < 8; ++u) {
            ax[u & 3] += bf2f((unsigned short)(v[u] & 0xffffu));
            ay[u & 3] += bf2f((unsigned short)(v[u] >> 16));
        }
    }
    for (; p < e; ++p) {
        unsigned int v = ((const unsigned int*)(t + (size_t)adjs[p] * HID))[lane];
        ax[0] += bf2f((unsigned short)(v & 0xffffu));
        ay[0] += bf2f((unsigned short)(v >> 16));
    }
    float dn = dinv[node];
    float ox = fmaxf(((ax[0] + ax[1]) + (ax[2] + ax[3])) * dn + bias[lane * 2], 0.f);
    float oy = fmaxf(((ay[0] + ay[1]) + (ay[2] + ay[3])) * dn + bias[lane * 2 + 1], 0.f);
    unsigned int pk = (unsigned int)f2bf(ox) | ((unsigned int)f2bf(oy) << 16);
    ((unsigned int*)(h + (size_t)node * HID))[lane] = pk;
}

// ---------------- segment mean-pool: one wave per graph, 8-deep unroll -------
__global__ __launch_bounds__(256) void k_pool(const unsigned short* __restrict__ h,
                                              const int* __restrict__ gstart,
                                              float* __restrict__ pbuf,
                                              int layer, int G) {
    int g = blockIdx.x * 4 + (threadIdx.x >> 6);
    if (g >= G) return;
    int lane = threadIdx.x & 63;
    int s = gstart[g], e = gstart[g + 1];
    float sx[4] = {0.f, 0.f, 0.f, 0.f};
    float sy[4] = {0.f, 0.f, 0.f, 0.f};
    int v = s;
    for (; v + 7 < e; v += 8) {
        unsigned int pk[8];
#pragma unroll
        for (int u = 0; u < 8; ++u)
            pk[u] = ((const unsigned int*)(h + (size_t)(v + u) * HID))[lane];
#pragma unroll
        for (int u = 0; u < 8; ++u) {
            sx[u & 3] += bf2f((unsigned short)(pk[u] & 0xffffu));
            sy[u & 3] += bf2f((unsigned short)(pk[u] >> 16));
        }
    }
    for (; v < e; ++v) {
        unsigned int pk = ((const unsigned int*)(h + (size_t)v * HID))[lane];
        sx[0] += bf2f((unsigned short)(pk & 0xffffu));
        sy[0] += bf2f((unsigned short)(pk >> 16));
    }
    float inv = 1.0f / fmaxf((float)(e - s), 1.0f);
    float ox = ((sx[0] + sx[1]) + (sx[2] + sx[3])) * inv;
    float oy = ((sy[0] + sy[1]) + (sy[2] + sy[3])) * inv;
    float* dst = pbuf + (size_t)g * 640 + layer * HID + lane * 2;
    dst[0] = ox;
    dst[1] = oy;
}

// ---------------- MLP head: Z[G,640] = relu(P[G,640] @ Wl1 + bl1) ------------
__global__ __launch_bounds__(256) void k_head1(const float* __restrict__ P,
                                               const float* __restrict__ Wl1,
                                               const float* __restrict__ bl1,
                                               float* __restrict__ Z, int G) {
    __shared__ float As[64][68];
    __shared__ float Ws[64][64];
    const int tid = threadIdx.x;
    const int tr = tid >> 4;
    const int tc = tid & 15;
    const int gBase = blockIdx.x * 64;
    const int cBase = blockIdx.y * 64;

    float acc[4][4];
#pragma unroll
    for (int i = 0; i < 4; ++i)
#pragma unroll
        for (int j = 0; j < 4; ++j) acc[i][j] = 0.f;

    for (int kb = 0; kb < 640; kb += 64) {
#pragma unroll
        for (int i = 0; i < 4; ++i) {
            int f4 = tid + i * 256;
            int r  = f4 >> 4;
            int kc = (f4 & 15) << 2;
            int gg = gBase + r;
            float4 v = {0.f, 0.f, 0.f, 0.f};
            if (gg < G) v = *(const float4*)(P + (size_t)gg * 640 + kb + kc);
            As[kc + 0][r] = v.x; As[kc + 1][r] = v.y;
            As[kc + 2][r] = v.z; As[kc + 3][r] = v.w;
        }
#pragma unroll
        for (int i = 0; i < 4; ++i) {
            int f4 = tid + i * 256;
            int k  = f4 >> 4;
            int c4 = (f4 & 15) << 2;
            *(float4*)&Ws[k][c4] =
                *(const float4*)(Wl1 + (size_t)(kb + k) * 640 + cBase + c4);
        }
        __syncthreads();
#pragma unroll
        for (int k = 0; k < 64; ++k) {
            float a[4], w[4];
            *(float4*)&a[0] = *(const float4*)&As[k][tr * 4];
            *(float4*)&w[0] = *(const float4*)&Ws[k][tc * 4];
#pragma unroll
            for (int i = 0; i < 4; ++i)
#pragma unroll
                for (int j = 0; j < 4; ++j)
                    acc[i][j] = fmaf(a[i], w[j], acc[i][j]);
        }
        __syncthreads();
    }
#pragma unroll
    for (int i = 0; i < 4; ++i) {
        int gg = gBase + tr * 4 + i;
        if (gg < G) {
            float4 o;
            o.x = fmaxf(acc[i][0] + bl1[cBase + tc * 4 + 0], 0.f);
            o.y = fmaxf(acc[i][1] + bl1[cBase + tc * 4 + 1], 0.f);
            o.z = fmaxf(acc[i][2] + bl1[cBase + tc * 4 + 2], 0.f);
            o.w = fmaxf(acc[i][3] + bl1[cBase + tc * 4 + 3], 0.f);
            *(float4*)(Z + (size_t)gg * 640 + cBase + tc * 4) = o;
        }
    }
}

__global__ void k_fc2(const float* __restrict__ zbuf, const float* __restrict__ Wl2,
                      const float* __restrict__ bl2, float* __restrict__ out) {
    int g = blockIdx.x;
    int t = threadIdx.x;  // 128 threads = 2 waves
    float s = 0.f;
    for (int k = t; k < 640; k += 128) s = fmaf(zbuf[(size_t)g * 640 + k], Wl2[k], s);
#pragma unroll
    for (int off = 32; off > 0; off >>= 1) s += __shfl_down(s, off);
    __shared__ float ws[2];
    if ((t & 63) == 0) ws[t >> 6] = s;
    __syncthreads();
    if (t == 0) out[g] = ws[0] + ws[1] + bl2[0];
}

// ---------------- driver ----------------
extern "C" void kernel_launch(void* const* d_in, const int* in_sizes, int n_in,
                              void* d_out, int out_size, void* d_ws, size_t ws_size,
                              hipStream_t stream) {
    const float* x    = (const float*)d_in[0];
    const int*   edge = (const int*)d_in[1];
    const int*   bat  = (const int*)d_in[2];
    const float* W1   = (const float*)d_in[3];
    const float* b1   = (const float*)d_in[4];
    const float* W2   = (const float*)d_in[5];
    const float* b2   = (const float*)d_in[6];
    const float* W3   = (const float*)d_in[7];
    const float* b3   = (const float*)d_in[8];
    const float* W4   = (const float*)d_in[9];
    const float* b4   = (const float*)d_in[10];
    const float* Wl1  = (const float*)d_in[11];
    const float* bl1  = (const float*)d_in[12];
    const float* Wl2  = (const float*)d_in[13];
    const float* bl2  = (const float*)d_in[14];
    float*       out  = (float*)d_out;

    const int N = in_sizes[2];       // 100000
    const int E = in_sizes[1] / 2;   // 1600000
    const int G = out_size;          // 512
    (void)n_in; (void)ws_size;

    (void)hipGetLastError();  // clear any stale error

    // ---- workspace carve ----
    size_t off = 0;
    auto alloc = [&](size_t bytes) -> void* {
        void* p = (void*)((char*)d_ws + off);
        off += (bytes + 255) & ~(size_t)255;
        return p;
    };
    unsigned short* buf0 = (unsigned short*)alloc((size_t)N * HID * 2);  // t', bf16
    unsigned short* buf1 = (unsigned short*)alloc((size_t)N * HID * 2);  // h, bf16
    unsigned short* Wg   = (unsigned short*)alloc((size_t)4 * 16384 * 2); // swizzled W1..4
    float* dinv   = (float*)alloc((size_t)N * 4);
    int*   degI   = (int*)alloc((size_t)N * 4);
    int*   cursor = (int*)alloc((size_t)N * 4);
    int*   indptr = (int*)alloc((size_t)(N + 1) * 4);
    int*   partial= (int*)alloc((size_t)N * 4);
    int*   bsums  = (int*)alloc((size_t)1024 * 4);
    int*   adjs   = (int*)alloc((size_t)(E + N) * 4);
    int*   gstart = (int*)alloc((size_t)(G + 1) * 4);
    float* pbuf   = (float*)alloc((size_t)G * 640 * 4);
    float* zbuf   = (float*)alloc((size_t)G * 640 * 4);

    const int* rowv = edge;      // sources
    const int* colv = edge + E;  // destinations

    // ---- preprocessing ----
    hipMemsetAsync(degI, 0, (size_t)N * 4, stream);
    k_deg<<<(E + 255) / 256, 256, 0, stream>>>(colv, degI, E);
    k_wprep<<<256, 256, 0, stream>>>(W1, W2, W3, W4, Wg);
    const int scanBlocks = (N + 1023) / 1024;
    k_scan_part<<<scanBlocks, 1024, 0, stream>>>(degI, partial, bsums, N);
    k_scan_tops<<<1, 1024, 0, stream>>>(bsums, indptr, scanBlocks, N);
    k_scan_fix<<<(N + 255) / 256, 256, 0, stream>>>(partial, bsums, degI,
                                                    indptr, cursor, dinv, N);
    k_gbounds<<<(G + 256) / 256, 256, 0, stream>>>(bat, gstart, N, G);

    // ---- fused: layer-0 GEMM + CSR scatter (independent; overlap) ----
    const int gemmGrid = (N + 127) / 128;
    const int scatGrid = (E + N + 255) / 256;
    k_fused0<<<gemmGrid + scatGrid, 256, 0, stream>>>(x, Wg, dinv, buf0, rowv, colv,
                                                      cursor, adjs, E, N, gemmGrid);

    // ---- 5 GCN layers (layer 5 reuses W4/b4, matching the reference) ----
    const float* bs_[5] = {b1, b2, b3, b4, b4};
    const int Wi_[5] = {0, 1, 2, 3, 3};
    const int aggGrid  = (N + 3) / 4;
    const int poolGrid = (G + 3) / 4;
    for (int L = 0; L < 5; ++L) {
        if (L > 0)
            k_gemm_mfma<<<gemmGrid, 256, 0, stream>>>(buf1, Wg + Wi_[L] * 16384,
                                                      dinv, buf0, N);
        k_aggregate<<<aggGrid, 256, 0, stream>>>(buf0, indptr, adjs, dinv,
                                                 bs_[L], buf1, N);
        k_pool<<<poolGrid, 256, 0, stream>>>(buf1, gstart, pbuf, L, G);
    }

    // ---- MLP head ----
    dim3 hgrid((G + 63) / 64, 10);   // 640 output cols / 64
    k_head1<<<hgrid, 256, 0, stream>>>(pbuf, Wl1, bl1, zbuf, G);
    k_fc2<<<G, 128, 0, stream>>>(zbuf, Wl2, bl2, out);

    // sentinel: some launch failed synchronously (absmax ~= 48)
    if (hipGetLastError() != hipSuccess)
        hipMemsetAsync(d_out, 0x42, (size_t)out_size * 4, stream);
}

// Round 11
// 907.354 us; speedup vs baseline: 1.0067x; 1.0067x over previous
//
#include <hip/hip_runtime.h>

#define HID 128   // feature width (D == H == 128)

// ---------------- bf16 helpers ----------------
__device__ __forceinline__ float bf2f(unsigned short u) {
    union { unsigned int i; float f; } v;
    v.i = ((unsigned int)u) << 16;
    return v.f;
}
__device__ __forceinline__ unsigned short f2bf(float f) {
    union { float f; unsigned int i; } v;
    v.f = f;
    unsigned int lsb = (v.i >> 16) & 1u;
    v.i += 0x7fffu + lsb;   // round-to-nearest-even
    return (unsigned short)(v.i >> 16);
}

typedef __attribute__((ext_vector_type(8))) short bf16x8;   // 8 bf16 (4 VGPRs)
typedef __attribute__((ext_vector_type(4))) float f32x4;    // MFMA acc

// ---------------- preprocessing ----------------
__global__ void k_deg(const int* __restrict__ col, int* __restrict__ degI, int E) {
    int i = blockIdx.x * blockDim.x + threadIdx.x;
    if (i < E) atomicAdd(&degI[col[i]], 1);
}

// ---- 3-phase device-wide exclusive scan of (degI[i]+1) -> indptr, cursor ----
__global__ void k_scan_part(const int* __restrict__ degI, int* __restrict__ partial,
                            int* __restrict__ sums, int N) {
    __shared__ int sh[1024];
    int tid = threadIdx.x;
    int i = blockIdx.x * 1024 + tid;
    int v = (i < N) ? (degI[i] + 1) : 0;
    sh[tid] = v;
    __syncthreads();
    for (int off = 1; off < 1024; off <<= 1) {
        int t = (tid >= off) ? sh[tid - off] : 0;
        __syncthreads();
        sh[tid] += t;
        __syncthreads();
    }
    if (i < N) partial[i] = sh[tid] - v;
    if (tid == 1023) sums[blockIdx.x] = sh[1023];
}
__global__ void k_scan_tops(int* __restrict__ sums, int* __restrict__ indptr,
                            int nblocks, int N) {
    __shared__ int sh[1024];
    int tid = threadIdx.x;
    int v = (tid < nblocks) ? sums[tid] : 0;
    sh[tid] = v;
    __syncthreads();
    for (int off = 1; off < 1024; off <<= 1) {
        int t = (tid >= off) ? sh[tid - off] : 0;
        __syncthreads();
        sh[tid] += t;
        __syncthreads();
    }
    if (tid < nblocks) sums[tid] = sh[tid] - v;   // exclusive
    if (tid == 1023) indptr[N] = sh[1023];        // grand total = E + N
}
// phase 3: emit indptr + cursor + dinv = 1/sqrt(deg+1)
__global__ void k_scan_fix(const int* __restrict__ partial, const int* __restrict__ sums,
                           const int* __restrict__ degI, int* __restrict__ indptr,
                           int* __restrict__ cursor, float* __restrict__ dinv, int N) {
    int i = blockIdx.x * blockDim.x + threadIdx.x;
    if (i < N) {
        int ex = partial[i] + sums[i >> 10];
        indptr[i] = ex;
        cursor[i] = ex;
        dinv[i] = 1.0f / sqrtf((float)(degI[i] + 1));
    }
}

// batch is SORTED -> graph segment bounds via binary search
__global__ void k_gbounds(const int* __restrict__ batch, int* __restrict__ gstart,
                          int N, int G) {
    int g = blockIdx.x * blockDim.x + threadIdx.x;
    if (g > G) return;
    int lo = 0, hi = N;
    while (lo < hi) {
        int mid = (lo + hi) >> 1;
        if (batch[mid] < g) lo = mid + 1; else hi = mid;
    }
    gstart[g] = lo;
}

// ---- pre-swizzle W1..W4 (f32, k-major) into B-fragment-ordered bf16 ----
__global__ void k_wprep(const float* __restrict__ W1, const float* __restrict__ W2,
                        const float* __restrict__ W3, const float* __restrict__ W4,
                        unsigned short* __restrict__ Wg) {
    int m = blockIdx.x >> 6;                       // matrix index 0..3
    int i = (blockIdx.x & 63) * 256 + threadIdx.x; // element 0..16383
    const float* Wm = (m == 0) ? W1 : (m == 1) ? W2 : (m == 2) ? W3 : W4;
    int k = i >> 7, n = i & 127;
    int ks = k >> 5, q = (k >> 3) & 3, j = k & 7;
    int ct = n >> 4, c = n & 15;
    Wg[m * 16384 + ((((ks * 8 + ct) * 4 + q) * 16 + c) << 3) + j] = f2bf(Wm[i]);
}

// ---------------- MFMA GEMM body ----------------
// B = fragment-ordered bf16 table (LDS in the fused kernel to isolate from
// scatter L2 contention; L2-direct in standalone layers where it's faster).
// Output scaled by dinv[row]: buf0 = (A@W)*dinv_row -> CSR needs src only.
__device__ __forceinline__ bf16x8 a_frag_load(const unsigned short* p) {
    return *(const bf16x8*)p;
}
__device__ __forceinline__ bf16x8 a_frag_load(const float* p) {
    bf16x8 r;
#pragma unroll
    for (int i = 0; i < 8; ++i) r[i] = (short)f2bf(p[i]);
    return r;
}

template <typename TA>
__device__ __forceinline__ void gemm_body(const TA* __restrict__ A,
                                          const unsigned short* __restrict__ B,
                                          const float* __restrict__ dinv,
                                          unsigned short* __restrict__ C,
                                          int N, int blk) {
    const int tid = threadIdx.x;
    const int lane = tid & 63, wave = tid >> 6;
    const int q = lane >> 4, c = lane & 15;
    const int rowBase = blk * 128 + wave * 32;

    f32x4 acc[2][8];
#pragma unroll
    for (int rt = 0; rt < 2; ++rt)
#pragma unroll
        for (int ct = 0; ct < 8; ++ct)
            acc[rt][ct] = (f32x4){0.f, 0.f, 0.f, 0.f};

    const bf16x8 zfrag = {};
#pragma unroll
    for (int ks = 0; ks < 4; ++ks) {
        bf16x8 a[2];
#pragma unroll
        for (int rt = 0; rt < 2; ++rt) {
            int r = rowBase + rt * 16 + c;
            a[rt] = (r < N) ? a_frag_load(A + (size_t)r * HID + ks * 32 + q * 8)
                            : zfrag;
        }
#pragma unroll
        for (int ct = 0; ct < 8; ++ct) {
            bf16x8 b = *(const bf16x8*)&B[((((ks * 8 + ct) * 4 + q) * 16 + c) << 3)];
            acc[0][ct] = __builtin_amdgcn_mfma_f32_16x16x32_bf16(a[0], b, acc[0][ct], 0, 0, 0);
            acc[1][ct] = __builtin_amdgcn_mfma_f32_16x16x32_bf16(a[1], b, acc[1][ct], 0, 0, 0);
        }
    }
#pragma unroll
    for (int rt = 0; rt < 2; ++rt)
#pragma unroll
        for (int reg = 0; reg < 4; ++reg) {
            int r = rowBase + rt * 16 + q * 4 + reg;
            if (r < N) {
                float s = dinv[r];
#pragma unroll
                for (int ct = 0; ct < 8; ++ct)
                    C[(size_t)r * HID + ct * 16 + c] = f2bf(acc[rt][ct][reg] * s);
            }
        }
}

// fat kernel: layer-0 GEMM (LDS-staged W) + flat CSR scatter (4B src entries)
__global__ __launch_bounds__(256) void k_fused0(const float* __restrict__ x,
                                                const unsigned short* __restrict__ Wg,
                                                const float* __restrict__ dinv,
                                                unsigned short* __restrict__ buf0,
                                                const int* __restrict__ row,
                                                const int* __restrict__ col,
                                                int* __restrict__ cursor,
                                                int* __restrict__ adjs,
                                                int E, int N, int gemmGrid) {
    __shared__ unsigned short Wsw[16384];   // 32 KB (gemm blocks only)
    if (blockIdx.x < gemmGrid) {
        // straight 16B copy of the pre-swizzled table (no conversion, no
        // bank conflicts) -> B reads hit LDS, immune to scatter RMW traffic
        const uint4* src = (const uint4*)Wg;
        uint4* dst = (uint4*)Wsw;
        for (int i = threadIdx.x; i < 2048; i += 256) dst[i] = src[i];
        __syncthreads();
        gemm_body<float>(x, Wsw, dinv, buf0, N, blockIdx.x);
        return;
    }
    int e = (blockIdx.x - gemmGrid) * blockDim.x + threadIdx.x;
    if (e >= E + N) return;
    int s, d;
    if (e < E) { s = row[e]; d = col[e]; }
    else       { s = d = e - E; }          // self loop
    int p = atomicAdd(&cursor[d], 1);
    adjs[p] = s;                            // norm folded into t'/epilogue
}

// layers 1..4 GEMM (A is bf16; B fragments L2-direct — faster standalone)
__global__ __launch_bounds__(256) void k_gemm_mfma(const unsigned short* __restrict__ A,
                                                   const unsigned short* __restrict__ Wg,
                                                   const float* __restrict__ dinv,
                                                   unsigned short* __restrict__ C,
                                                   int N) {
    gemm_body<unsigned short>(A, Wg, dinv, C, N, blockIdx.x);
}

// ---------------- CSR gather-aggregate + dinv[d]*sum + bias + ReLU -----------
__global__ __launch_bounds__(256) void k_aggregate(const unsigned short* __restrict__ t,
                                                   const int* __restrict__ indptr,
                                                   const int* __restrict__ adjs,
                                                   const float* __restrict__ dinv,
                                                   const float* __restrict__ bias,
                                                   unsigned short* __restrict__ h, int N) {
    int node = blockIdx.x * 4 + (threadIdx.x >> 6);
    if (node >= N) return;
    int lane = threadIdx.x & 63;
    int s = indptr[node], e = indptr[node + 1];
    float ax[4] = {0.f, 0.f, 0.f, 0.f};
    float ay[4] = {0.f, 0.f, 0.f, 0.f};
    int p = s;
    for (; p + 7 < e; p += 8) {
        unsigned int v[8];
#pragma unroll
        for (int u = 0; u < 8; ++u) {
            int ss = adjs[p + u];
            v[u] = ((const unsigned int*)(t + (size_t)ss * HID))[lane];
        }
#pragma unroll
        for (int u = 0; u < 8; ++u) {
            ax[u & 3] += bf2f((unsigned short)(v[u] & 0xffffu));
            ay[u & 3] += bf2f((unsigned short)(v[u] >> 16));
        }
    }
    for (; p < e; ++p) {
        unsigned int v = ((const unsigned int*)(t + (size_t)adjs[p] * HID))[lane];
        ax[0] += bf2f((unsigned short)(v & 0xffffu));
        ay[0] += bf2f((unsigned short)(v >> 16));
    }
    float dn = dinv[node];
    float ox = fmaxf(((ax[0] + ax[1]) + (ax[2] + ax[3])) * dn + bias[lane * 2], 0.f);
    float oy = fmaxf(((ay[0] + ay[1]) + (ay[2] + ay[3])) * dn + bias[lane * 2 + 1], 0.f);
    unsigned int pk = (unsigned int)f2bf(ox) | ((unsigned int)f2bf(oy) << 16);
    ((unsigned int*)(h + (size_t)node * HID))[lane] = pk;
}

// ---------------- segment mean-pool: one wave per graph, 8-deep unroll -------
__global__ __launch_bounds__(256) void k_pool(const unsigned short* __restrict__ h,
                                              const int* __restrict__ gstart,
                                              float* __restrict__ pbuf,
                                              int layer, int G) {
    int g = blockIdx.x * 4 + (threadIdx.x >> 6);
    if (g >= G) return;
    int lane = threadIdx.x & 63;
    int s = gstart[g], e = gstart[g + 1];
    float sx[4] = {0.f, 0.f, 0.f, 0.f};
    float sy[4] = {0.f, 0.f, 0.f, 0.f};
    int v = s;
    for (; v + 7 < e; v += 8) {
        unsigned int pk[8];
#pragma unroll
        for (int u = 0; u < 8; ++u)
            pk[u] = ((const unsigned int*)(h + (size_t)(v + u) * HID))[lane];
#pragma unroll
        for (int u = 0; u < 8; ++u) {
            sx[u & 3] += bf2f((unsigned short)(pk[u] & 0xffffu));
            sy[u & 3] += bf2f((unsigned short)(pk[u] >> 16));
        }
    }
    for (; v < e; ++v) {
        unsigned int pk = ((const unsigned int*)(h + (size_t)v * HID))[lane];
        sx[0] += bf2f((unsigned short)(pk & 0xffffu));
        sy[0] += bf2f((unsigned short)(pk >> 16));
    }
    float inv = 1.0f / fmaxf((float)(e - s), 1.0f);
    float ox = ((sx[0] + sx[1]) + (sx[2] + sx[3])) * inv;
    float oy = ((sy[0] + sy[1]) + (sy[2] + sy[3])) * inv;
    float* dst = pbuf + (size_t)g * 640 + layer * HID + lane * 2;
    dst[0] = ox;
    dst[1] = oy;
}

// ---------------- MLP head: Z[G,640] = relu(P[G,640] @ Wl1 + bl1) ------------
__global__ __launch_bounds__(256) void k_head1(const float* __restrict__ P,
                                               const float* __restrict__ Wl1,
                                               const float* __restrict__ bl1,
                                               float* __restrict__ Z, int G) {
    __shared__ float As[64][68];
    __shared__ float Ws[64][64];
    const int tid = threadIdx.x;
    const int tr = tid >> 4;
    const int tc = tid & 15;
    const int gBase = blockIdx.x * 64;
    const int cBase = blockIdx.y * 64;

    float acc[4][4];
#pragma unroll
    for (int i = 0; i < 4; ++i)
#pragma unroll
        for (int j = 0; j < 4; ++j) acc[i][j] = 0.f;

    for (int kb = 0; kb < 640; kb += 64) {
#pragma unroll
        for (int i = 0; i < 4; ++i) {
            int f4 = tid + i * 256;
            int r  = f4 >> 4;
            int kc = (f4 & 15) << 2;
            int gg = gBase + r;
            float4 v = {0.f, 0.f, 0.f, 0.f};
            if (gg < G) v = *(const float4*)(P + (size_t)gg * 640 + kb + kc);
            As[kc + 0][r] = v.x; As[kc + 1][r] = v.y;
            As[kc + 2][r] = v.z; As[kc + 3][r] = v.w;
        }
#pragma unroll
        for (int i = 0; i < 4; ++i) {
            int f4 = tid + i * 256;
            int k  = f4 >> 4;
            int c4 = (f4 & 15) << 2;
            *(float4*)&Ws[k][c4] =
                *(const float4*)(Wl1 + (size_t)(kb + k) * 640 + cBase + c4);
        }
        __syncthreads();
#pragma unroll
        for (int k = 0; k < 64; ++k) {
            float a[4], w[4];
            *(float4*)&a[0] = *(const float4*)&As[k][tr * 4];
            *(float4*)&w[0] = *(const float4*)&Ws[k][tc * 4];
#pragma unroll
            for (int i = 0; i < 4; ++i)
#pragma unroll
                for (int j = 0; j < 4; ++j)
                    acc[i][j] = fmaf(a[i], w[j], acc[i][j]);
        }
        __syncthreads();
    }
#pragma unroll
    for (int i = 0; i < 4; ++i) {
        int gg = gBase + tr * 4 + i;
        if (gg < G) {
            float4 o;
            o.x = fmaxf(acc[i][0] + bl1[cBase + tc * 4 + 0], 0.f);
            o.y = fmaxf(acc[i][1] + bl1[cBase + tc * 4 + 1], 0.f);
            o.z = fmaxf(acc[i][2] + bl1[cBase + tc * 4 + 2], 0.f);
            o.w = fmaxf(acc[i][3] + bl1[cBase + tc * 4 + 3], 0.f);
            *(float4*)(Z + (size_t)gg * 640 + cBase + tc * 4) = o;
        }
    }
}

__global__ void k_fc2(const float* __restrict__ zbuf, const float* __restrict__ Wl2,
                      const float* __restrict__ bl2, float* __restrict__ out) {
    int g = blockIdx.x;
    int t = threadIdx.x;  // 128 threads = 2 waves
    float s = 0.f;
    for (int k = t; k < 640; k += 128) s = fmaf(zbuf[(size_t)g * 640 + k], Wl2[k], s);
#pragma unroll
    for (int off = 32; off > 0; off >>= 1) s += __shfl_down(s, off);
    __shared__ float ws[2];
    if ((t & 63) == 0) ws[t >> 6] = s;
    __syncthreads();
    if (t == 0) out[g] = ws[0] + ws[1] + bl2[0];
}

// ---------------- driver ----------------
extern "C" void kernel_launch(void* const* d_in, const int* in_sizes, int n_in,
                              void* d_out, int out_size, void* d_ws, size_t ws_size,
                              hipStream_t stream) {
    const float* x    = (const float*)d_in[0];
    const int*   edge = (const int*)d_in[1];
    const int*   bat  = (const int*)d_in[2];
    const float* W1   = (const float*)d_in[3];
    const float* b1   = (const float*)d_in[4];
    const float* W2   = (const float*)d_in[5];
    const float* b2   = (const float*)d_in[6];
    const float* W3   = (const float*)d_in[7];
    const float* b3   = (const float*)d_in[8];
    const float* W4   = (const float*)d_in[9];
    const float* b4   = (const float*)d_in[10];
    const float* Wl1  = (const float*)d_in[11];
    const float* bl1  = (const float*)d_in[12];
    const float* Wl2  = (const float*)d_in[13];
    const float* bl2  = (const float*)d_in[14];
    float*       out  = (float*)d_out;

    const int N = in_sizes[2];       // 100000
    const int E = in_sizes[1] / 2;   // 1600000
    const int G = out_size;          // 512
    (void)n_in; (void)ws_size;

    (void)hipGetLastError();  // clear any stale error

    // ---- workspace carve ----
    size_t off = 0;
    auto alloc = [&](size_t bytes) -> void* {
        void* p = (void*)((char*)d_ws + off);
        off += (bytes + 255) & ~(size_t)255;
        return p;
    };
    unsigned short* buf0 = (unsigned short*)alloc((size_t)N * HID * 2);  // t', bf16
    unsigned short* buf1 = (unsigned short*)alloc((size_t)N * HID * 2);  // h, bf16
    unsigned short* Wg   = (unsigned short*)alloc((size_t)4 * 16384 * 2); // swizzled W1..4
    float* dinv   = (float*)alloc((size_t)N * 4);
    int*   degI   = (int*)alloc((size_t)N * 4);
    int*   cursor = (int*)alloc((size_t)N * 4);
    int*   indptr = (int*)alloc((size_t)(N + 1) * 4);
    int*   partial= (int*)alloc((size_t)N * 4);
    int*   bsums  = (int*)alloc((size_t)1024 * 4);
    int*   adjs   = (int*)alloc((size_t)(E + N) * 4);
    int*   gstart = (int*)alloc((size_t)(G + 1) * 4);
    float* pbuf   = (float*)alloc((size_t)G * 640 * 4);
    float* zbuf   = (float*)alloc((size_t)G * 640 * 4);

    const int* rowv = edge;      // sources
    const int* colv = edge + E;  // destinations

    // ---- preprocessing ----
    hipMemsetAsync(degI, 0, (size_t)N * 4, stream);
    k_deg<<<(E + 255) / 256, 256, 0, stream>>>(colv, degI, E);
    k_wprep<<<256, 256, 0, stream>>>(W1, W2, W3, W4, Wg);
    const int scanBlocks = (N + 1023) / 1024;
    k_scan_part<<<scanBlocks, 1024, 0, stream>>>(degI, partial, bsums, N);
    k_scan_tops<<<1, 1024, 0, stream>>>(bsums, indptr, scanBlocks, N);
    k_scan_fix<<<(N + 255) / 256, 256, 0, stream>>>(partial, bsums, degI,
                                                    indptr, cursor, dinv, N);
    k_gbounds<<<(G + 256) / 256, 256, 0, stream>>>(bat, gstart, N, G);

    // ---- fused: layer-0 GEMM (LDS W) + CSR scatter (overlap) ----
    const int gemmGrid = (N + 127) / 128;
    const int scatGrid = (E + N + 255) / 256;
    k_fused0<<<gemmGrid + scatGrid, 256, 0, stream>>>(x, Wg, dinv, buf0, rowv, colv,
                                                      cursor, adjs, E, N, gemmGrid);

    // ---- 5 GCN layers (layer 5 reuses W4/b4, matching the reference) ----
    const float* bs_[5] = {b1, b2, b3, b4, b4};
    const int Wi_[5] = {0, 1, 2, 3, 3};
    const int aggGrid  = (N + 3) / 4;
    const int poolGrid = (G + 3) / 4;
    for (int L = 0; L < 5; ++L) {
        if (L > 0)
            k_gemm_mfma<<<gemmGrid, 256, 0, stream>>>(buf1, Wg + Wi_[L] * 16384,
                                                      dinv, buf0, N);
        k_aggregate<<<aggGrid, 256, 0, stream>>>(buf0, indptr, adjs, dinv,
                                                 bs_[L], buf1, N);
        k_pool<<<poolGrid, 256, 0, stream>>>(buf1, gstart, pbuf, L, G);
    }

    // ---- MLP head ----
    dim3 hgrid((G + 63) / 64, 10);   // 640 output cols / 64
    k_head1<<<hgrid, 256, 0, stream>>>(pbuf, Wl1, bl1, zbuf, G);
    k_fc2<<<G, 128, 0, stream>>>(zbuf, Wl2, bl2, out);

    // sentinel: some launch failed synchronously (absmax ~= 48)
    if (hipGetLastError() != hipSuccess)
        hipMemsetAsync(d_out, 0x42, (size_t)out_size * 4, stream);
}

// Round 12
// 854.022 us; speedup vs baseline: 1.0695x; 1.0624x over previous
//
#include <hip/hip_runtime.h>

#define HID 128   // feature width (D == H == 128)

// ---------------- bf16 helpers ----------------
__device__ __forceinline__ float bf2f(unsigned short u) {
    union { unsigned int i; float f; } v;
    v.i = ((unsigned int)u) << 16;
    return v.f;
}
__device__ __forceinline__ unsigned short f2bf(float f) {
    union { float f; unsigned int i; } v;
    v.f = f;
    unsigned int lsb = (v.i >> 16) & 1u;
    v.i += 0x7fffu + lsb;   // round-to-nearest-even
    return (unsigned short)(v.i >> 16);
}

typedef __attribute__((ext_vector_type(8))) short bf16x8;   // 8 bf16 (4 VGPRs)
typedef __attribute__((ext_vector_type(4))) float f32x4;    // MFMA acc

// ---------------- preprocessing ----------------
__global__ void k_deg(const int* __restrict__ col, int* __restrict__ degI, int E) {
    int i = blockIdx.x * blockDim.x + threadIdx.x;
    if (i < E) atomicAdd(&degI[col[i]], 1);
}

// ---- 3-phase device-wide exclusive scan of (degI[i]+1) -> indptr, cursor ----
__global__ void k_scan_part(const int* __restrict__ degI, int* __restrict__ partial,
                            int* __restrict__ sums, int N) {
    __shared__ int sh[1024];
    int tid = threadIdx.x;
    int i = blockIdx.x * 1024 + tid;
    int v = (i < N) ? (degI[i] + 1) : 0;
    sh[tid] = v;
    __syncthreads();
    for (int off = 1; off < 1024; off <<= 1) {
        int t = (tid >= off) ? sh[tid - off] : 0;
        __syncthreads();
        sh[tid] += t;
        __syncthreads();
    }
    if (i < N) partial[i] = sh[tid] - v;
    if (tid == 1023) sums[blockIdx.x] = sh[1023];
}
__global__ void k_scan_tops(int* __restrict__ sums, int* __restrict__ indptr,
                            int nblocks, int N) {
    __shared__ int sh[1024];
    int tid = threadIdx.x;
    int v = (tid < nblocks) ? sums[tid] : 0;
    sh[tid] = v;
    __syncthreads();
    for (int off = 1; off < 1024; off <<= 1) {
        int t = (tid >= off) ? sh[tid - off] : 0;
        __syncthreads();
        sh[tid] += t;
        __syncthreads();
    }
    if (tid < nblocks) sums[tid] = sh[tid] - v;   // exclusive
    if (tid == 1023) indptr[N] = sh[1023];        // grand total = E + N
}
// phase 3: emit indptr + cursor + dinv = 1/sqrt(deg+1)
__global__ void k_scan_fix(const int* __restrict__ partial, const int* __restrict__ sums,
                           const int* __restrict__ degI, int* __restrict__ indptr,
                           int* __restrict__ cursor, float* __restrict__ dinv, int N) {
    int i = blockIdx.x * blockDim.x + threadIdx.x;
    if (i < N) {
        int ex = partial[i] + sums[i >> 10];
        indptr[i] = ex;
        cursor[i] = ex;
        dinv[i] = 1.0f / sqrtf((float)(degI[i] + 1));
    }
}

// batch is SORTED -> graph segment bounds via binary search
__global__ void k_gbounds(const int* __restrict__ batch, int* __restrict__ gstart,
                          int N, int G) {
    int g = blockIdx.x * blockDim.x + threadIdx.x;
    if (g > G) return;
    int lo = 0, hi = N;
    while (lo < hi) {
        int mid = (lo + hi) >> 1;
        if (batch[mid] < g) lo = mid + 1; else hi = mid;
    }
    gstart[g] = lo;
}

// ---- pre-swizzle W1..W4 (f32, k-major) into B-fragment-ordered bf16 ----
__global__ void k_wprep(const float* __restrict__ W1, const float* __restrict__ W2,
                        const float* __restrict__ W3, const float* __restrict__ W4,
                        unsigned short* __restrict__ Wg) {
    int m = blockIdx.x >> 6;                       // matrix index 0..3
    int i = (blockIdx.x & 63) * 256 + threadIdx.x; // element 0..16383
    const float* Wm = (m == 0) ? W1 : (m == 1) ? W2 : (m == 2) ? W3 : W4;
    int k = i >> 7, n = i & 127;
    int ks = k >> 5, q = (k >> 3) & 3, j = k & 7;
    int ct = n >> 4, c = n & 15;
    Wg[m * 16384 + ((((ks * 8 + ct) * 4 + q) * 16 + c) << 3) + j] = f2bf(Wm[i]);
}

// ---------------- MFMA GEMM body (C = A @ W, bf16 out, unscaled) -------------
__device__ __forceinline__ bf16x8 a_frag_load(const unsigned short* p) {
    return *(const bf16x8*)p;
}
__device__ __forceinline__ bf16x8 a_frag_load(const float* p) {
    bf16x8 r;
#pragma unroll
    for (int i = 0; i < 8; ++i) r[i] = (short)f2bf(p[i]);
    return r;
}

template <typename TA>
__device__ __forceinline__ void gemm_body(const TA* __restrict__ A,
                                          const unsigned short* __restrict__ B,
                                          unsigned short* __restrict__ C,
                                          int N, int blk) {
    const int tid = threadIdx.x;
    const int lane = tid & 63, wave = tid >> 6;
    const int q = lane >> 4, c = lane & 15;
    const int rowBase = blk * 128 + wave * 32;

    f32x4 acc[2][8];
#pragma unroll
    for (int rt = 0; rt < 2; ++rt)
#pragma unroll
        for (int ct = 0; ct < 8; ++ct)
            acc[rt][ct] = (f32x4){0.f, 0.f, 0.f, 0.f};

    const bf16x8 zfrag = {};
#pragma unroll
    for (int ks = 0; ks < 4; ++ks) {
        bf16x8 a[2];
#pragma unroll
        for (int rt = 0; rt < 2; ++rt) {
            int r = rowBase + rt * 16 + c;
            a[rt] = (r < N) ? a_frag_load(A + (size_t)r * HID + ks * 32 + q * 8)
                            : zfrag;
        }
#pragma unroll
        for (int ct = 0; ct < 8; ++ct) {
            bf16x8 b = *(const bf16x8*)&B[((((ks * 8 + ct) * 4 + q) * 16 + c) << 3)];
            acc[0][ct] = __builtin_amdgcn_mfma_f32_16x16x32_bf16(a[0], b, acc[0][ct], 0, 0, 0);
            acc[1][ct] = __builtin_amdgcn_mfma_f32_16x16x32_bf16(a[1], b, acc[1][ct], 0, 0, 0);
        }
    }
#pragma unroll
    for (int rt = 0; rt < 2; ++rt)
#pragma unroll
        for (int reg = 0; reg < 4; ++reg) {
            int r = rowBase + rt * 16 + q * 4 + reg;
            if (r < N) {
#pragma unroll
                for (int ct = 0; ct < 8; ++ct)
                    C[(size_t)r * HID + ct * 16 + c] = f2bf(acc[rt][ct][reg]);
            }
        }
}

// fat kernel: layer-0 GEMM (LDS-copied W) + flat CSR scatter.
// NOTE: adj entries are 8B int2 (src, norm). Empirical (r9 vs r10/r11): 8B
// stores run the scatter at ~100us; 4B stores at ~165us with IDENTICAL
// WRITE_SIZE -- per-line merge serialization doubles when 16 partial writes
// per line arrive from across XCDs instead of 8. Keep entries 8B.
__global__ __launch_bounds__(256) void k_fused0(const float* __restrict__ x,
                                                const unsigned short* __restrict__ Wg,
                                                unsigned short* __restrict__ buf0,
                                                const int* __restrict__ row,
                                                const int* __restrict__ col,
                                                const float* __restrict__ dinv,
                                                int* __restrict__ cursor,
                                                int2* __restrict__ adj,
                                                int E, int N, int gemmGrid) {
    __shared__ unsigned short Wsw[16384];   // 32 KB (gemm blocks only)
    if (blockIdx.x < gemmGrid) {
        const uint4* src = (const uint4*)Wg;   // straight 16B copy, 0 conflicts
        uint4* dst = (uint4*)Wsw;
        for (int i = threadIdx.x; i < 2048; i += 256) dst[i] = src[i];
        __syncthreads();
        gemm_body<float>(x, Wsw, buf0, N, blockIdx.x);
        return;
    }
    int e = (blockIdx.x - gemmGrid) * blockDim.x + threadIdx.x;
    if (e >= E + N) return;
    int s, d;
    if (e < E) { s = row[e]; d = col[e]; }
    else       { s = d = e - E; }          // self loop
    int p = atomicAdd(&cursor[d], 1);
    adj[p] = make_int2(s, __float_as_int(dinv[s] * dinv[d]));
}

// layers 1..4 GEMM (A is bf16; B fragments L2-direct — faster standalone)
__global__ __launch_bounds__(256) void k_gemm_mfma(const unsigned short* __restrict__ A,
                                                   const unsigned short* __restrict__ Wg,
                                                   unsigned short* __restrict__ C,
                                                   int N) {
    gemm_body<unsigned short>(A, Wg, C, N, blockIdx.x);
}

// ---------------- CSR gather-aggregate + bias + ReLU (weighted, r9 scheme) ---
__global__ __launch_bounds__(256) void k_aggregate(const unsigned short* __restrict__ t,
                                                   const int* __restrict__ indptr,
                                                   const int2* __restrict__ adj,
                                                   const float* __restrict__ bias,
                                                   unsigned short* __restrict__ h, int N) {
    int node = blockIdx.x * 4 + (threadIdx.x >> 6);
    if (node >= N) return;
    int lane = threadIdx.x & 63;
    int s = indptr[node], e = indptr[node + 1];
    float ax[4] = {0.f, 0.f, 0.f, 0.f};
    float ay[4] = {0.f, 0.f, 0.f, 0.f};
    int p = s;
    for (; p + 7 < e; p += 8) {
        unsigned int v[8];
        float w[8];
#pragma unroll
        for (int u = 0; u < 8; ++u) {
            int2 ae = adj[p + u];
            w[u] = __int_as_float(ae.y);
            v[u] = ((const unsigned int*)(t + (size_t)ae.x * HID))[lane];
        }
#pragma unroll
        for (int u = 0; u < 8; ++u) {
            float lo = bf2f((unsigned short)(v[u] & 0xffffu));
            float hi = bf2f((unsigned short)(v[u] >> 16));
            ax[u & 3] = fmaf(w[u], lo, ax[u & 3]);
            ay[u & 3] = fmaf(w[u], hi, ay[u & 3]);
        }
    }
    for (; p < e; ++p) {
        int2 ae = adj[p];
        float ww = __int_as_float(ae.y);
        unsigned int v = ((const unsigned int*)(t + (size_t)ae.x * HID))[lane];
        ax[0] = fmaf(ww, bf2f((unsigned short)(v & 0xffffu)), ax[0]);
        ay[0] = fmaf(ww, bf2f((unsigned short)(v >> 16)), ay[0]);
    }
    float ox = fmaxf((ax[0] + ax[1]) + (ax[2] + ax[3]) + bias[lane * 2], 0.f);
    float oy = fmaxf((ay[0] + ay[1]) + (ay[2] + ay[3]) + bias[lane * 2 + 1], 0.f);
    unsigned int pk = (unsigned int)f2bf(ox) | ((unsigned int)f2bf(oy) << 16);
    ((unsigned int*)(h + (size_t)node * HID))[lane] = pk;
}

// ---------------- segment mean-pool: one wave per graph, 8-deep unroll -------
__global__ __launch_bounds__(256) void k_pool(const unsigned short* __restrict__ h,
                                              const int* __restrict__ gstart,
                                              float* __restrict__ pbuf,
                                              int layer, int G) {
    int g = blockIdx.x * 4 + (threadIdx.x >> 6);
    if (g >= G) return;
    int lane = threadIdx.x & 63;
    int s = gstart[g], e = gstart[g + 1];
    float sx[4] = {0.f, 0.f, 0.f, 0.f};
    float sy[4] = {0.f, 0.f, 0.f, 0.f};
    int v = s;
    for (; v + 7 < e; v += 8) {
        unsigned int pk[8];
#pragma unroll
        for (int u = 0; u < 8; ++u)
            pk[u] = ((const unsigned int*)(h + (size_t)(v + u) * HID))[lane];
#pragma unroll
        for (int u = 0; u < 8; ++u) {
            sx[u & 3] += bf2f((unsigned short)(pk[u] & 0xffffu));
            sy[u & 3] += bf2f((unsigned short)(pk[u] >> 16));
        }
    }
    for (; v < e; ++v) {
        unsigned int pk = ((const unsigned int*)(h + (size_t)v * HID))[lane];
        sx[0] += bf2f((unsigned short)(pk & 0xffffu));
        sy[0] += bf2f((unsigned short)(pk >> 16));
    }
    float inv = 1.0f / fmaxf((float)(e - s), 1.0f);
    float ox = ((sx[0] + sx[1]) + (sx[2] + sx[3])) * inv;
    float oy = ((sy[0] + sy[1]) + (sy[2] + sy[3])) * inv;
    float* dst = pbuf + (size_t)g * 640 + layer * HID + lane * 2;
    dst[0] = ox;
    dst[1] = oy;
}

// ---------------- MLP head: Z[G,640] = relu(P[G,640] @ Wl1 + bl1) ------------
__global__ __launch_bounds__(256) void k_head1(const float* __restrict__ P,
                                               const float* __restrict__ Wl1,
                                               const float* __restrict__ bl1,
                                               float* __restrict__ Z, int G) {
    __shared__ float As[64][68];
    __shared__ float Ws[64][64];
    const int tid = threadIdx.x;
    const int tr = tid >> 4;
    const int tc = tid & 15;
    const int gBase = blockIdx.x * 64;
    const int cBase = blockIdx.y * 64;

    float acc[4][4];
#pragma unroll
    for (int i = 0; i < 4; ++i)
#pragma unroll
        for (int j = 0; j < 4; ++j) acc[i][j] = 0.f;

    for (int kb = 0; kb < 640; kb += 64) {
#pragma unroll
        for (int i = 0; i < 4; ++i) {
            int f4 = tid + i * 256;
            int r  = f4 >> 4;
            int kc = (f4 & 15) << 2;
            int gg = gBase + r;
            float4 v = {0.f, 0.f, 0.f, 0.f};
            if (gg < G) v = *(const float4*)(P + (size_t)gg * 640 + kb + kc);
            As[kc + 0][r] = v.x; As[kc + 1][r] = v.y;
            As[kc + 2][r] = v.z; As[kc + 3][r] = v.w;
        }
#pragma unroll
        for (int i = 0; i < 4; ++i) {
            int f4 = tid + i * 256;
            int k  = f4 >> 4;
            int c4 = (f4 & 15) << 2;
            *(float4*)&Ws[k][c4] =
                *(const float4*)(Wl1 + (size_t)(kb + k) * 640 + cBase + c4);
        }
        __syncthreads();
#pragma unroll
        for (int k = 0; k < 64; ++k) {
            float a[4], w[4];
            *(float4*)&a[0] = *(const float4*)&As[k][tr * 4];
            *(float4*)&w[0] = *(const float4*)&Ws[k][tc * 4];
#pragma unroll
            for (int i = 0; i < 4; ++i)
#pragma unroll
                for (int j = 0; j < 4; ++j)
                    acc[i][j] = fmaf(a[i], w[j], acc[i][j]);
        }
        __syncthreads();
    }
#pragma unroll
    for (int i = 0; i < 4; ++i) {
        int gg = gBase + tr * 4 + i;
        if (gg < G) {
            float4 o;
            o.x = fmaxf(acc[i][0] + bl1[cBase + tc * 4 + 0], 0.f);
            o.y = fmaxf(acc[i][1] + bl1[cBase + tc * 4 + 1], 0.f);
            o.z = fmaxf(acc[i][2] + bl1[cBase + tc * 4 + 2], 0.f);
            o.w = fmaxf(acc[i][3] + bl1[cBase + tc * 4 + 3], 0.f);
            *(float4*)(Z + (size_t)gg * 640 + cBase + tc * 4) = o;
        }
    }
}

__global__ void k_fc2(const float* __restrict__ zbuf, const float* __restrict__ Wl2,
                      const float* __restrict__ bl2, float* __restrict__ out) {
    int g = blockIdx.x;
    int t = threadIdx.x;  // 128 threads = 2 waves
    float s = 0.f;
    for (int k = t; k < 640; k += 128) s = fmaf(zbuf[(size_t)g * 640 + k], Wl2[k], s);
#pragma unroll
    for (int off = 32; off > 0; off >>= 1) s += __shfl_down(s, off);
    __shared__ float ws[2];
    if ((t & 63) == 0) ws[t >> 6] = s;
    __syncthreads();
    if (t == 0) out[g] = ws[0] + ws[1] + bl2[0];
}

// ---------------- driver ----------------
extern "C" void kernel_launch(void* const* d_in, const int* in_sizes, int n_in,
                              void* d_out, int out_size, void* d_ws, size_t ws_size,
                              hipStream_t stream) {
    const float* x    = (const float*)d_in[0];
    const int*   edge = (const int*)d_in[1];
    const int*   bat  = (const int*)d_in[2];
    const float* W1   = (const float*)d_in[3];
    const float* b1   = (const float*)d_in[4];
    const float* W2   = (const float*)d_in[5];
    const float* b2   = (const float*)d_in[6];
    const float* W3   = (const float*)d_in[7];
    const float* b3   = (const float*)d_in[8];
    const float* W4   = (const float*)d_in[9];
    const float* b4   = (const float*)d_in[10];
    const float* Wl1  = (const float*)d_in[11];
    const float* bl1  = (const float*)d_in[12];
    const float* Wl2  = (const float*)d_in[13];
    const float* bl2  = (const float*)d_in[14];
    float*       out  = (float*)d_out;

    const int N = in_sizes[2];       // 100000
    const int E = in_sizes[1] / 2;   // 1600000
    const int G = out_size;          // 512
    (void)n_in; (void)ws_size;

    (void)hipGetLastError();  // clear any stale error

    // ---- workspace carve ----
    size_t off = 0;
    auto alloc = [&](size_t bytes) -> void* {
        void* p = (void*)((char*)d_ws + off);
        off += (bytes + 255) & ~(size_t)255;
        return p;
    };
    unsigned short* buf0 = (unsigned short*)alloc((size_t)N * HID * 2);  // t, bf16
    unsigned short* buf1 = (unsigned short*)alloc((size_t)N * HID * 2);  // h, bf16
    unsigned short* Wg   = (unsigned short*)alloc((size_t)4 * 16384 * 2); // swizzled W1..4
    float* dinv   = (float*)alloc((size_t)N * 4);
    int*   degI   = (int*)alloc((size_t)N * 4);
    int*   cursor = (int*)alloc((size_t)N * 4);
    int*   indptr = (int*)alloc((size_t)(N + 1) * 4);
    int*   partial= (int*)alloc((size_t)N * 4);
    int*   bsums  = (int*)alloc((size_t)1024 * 4);
    int2*  adj    = (int2*)alloc((size_t)(E + N) * 8);
    int*   gstart = (int*)alloc((size_t)(G + 1) * 4);
    float* pbuf   = (float*)alloc((size_t)G * 640 * 4);
    float* zbuf   = (float*)alloc((size_t)G * 640 * 4);

    const int* rowv = edge;      // sources
    const int* colv = edge + E;  // destinations

    // ---- preprocessing ----
    hipMemsetAsync(degI, 0, (size_t)N * 4, stream);
    k_deg<<<(E + 255) / 256, 256, 0, stream>>>(colv, degI, E);
    k_wprep<<<256, 256, 0, stream>>>(W1, W2, W3, W4, Wg);
    const int scanBlocks = (N + 1023) / 1024;
    k_scan_part<<<scanBlocks, 1024, 0, stream>>>(degI, partial, bsums, N);
    k_scan_tops<<<1, 1024, 0, stream>>>(bsums, indptr, scanBlocks, N);
    k_scan_fix<<<(N + 255) / 256, 256, 0, stream>>>(partial, bsums, degI,
                                                    indptr, cursor, dinv, N);
    k_gbounds<<<(G + 256) / 256, 256, 0, stream>>>(bat, gstart, N, G);

    // ---- fused: layer-0 GEMM (LDS W) + CSR scatter (8B int2 entries) ----
    const int gemmGrid = (N + 127) / 128;
    const int scatGrid = (E + N + 255) / 256;
    k_fused0<<<gemmGrid + scatGrid, 256, 0, stream>>>(x, Wg, buf0, rowv, colv,
                                                      dinv, cursor, adj,
                                                      E, N, gemmGrid);

    // ---- 5 GCN layers (layer 5 reuses W4/b4, matching the reference) ----
    const float* bs_[5] = {b1, b2, b3, b4, b4};
    const int Wi_[5] = {0, 1, 2, 3, 3};
    const int aggGrid  = (N + 3) / 4;
    const int poolGrid = (G + 3) / 4;
    for (int L = 0; L < 5; ++L) {
        if (L > 0)
            k_gemm_mfma<<<gemmGrid, 256, 0, stream>>>(buf1, Wg + Wi_[L] * 16384,
                                                      buf0, N);
        k_aggregate<<<aggGrid, 256, 0, stream>>>(buf0, indptr, adj, bs_[L], buf1, N);
        k_pool<<<poolGrid, 256, 0, stream>>>(buf1, gstart, pbuf, L, G);
    }

    // ---- MLP head ----
    dim3 hgrid((G + 63) / 64, 10);   // 640 output cols / 64
    k_head1<<<hgrid, 256, 0, stream>>>(pbuf, Wl1, bl1, zbuf, G);
    k_fc2<<<G, 128, 0, stream>>>(zbuf, Wl2, bl2, out);

    // sentinel: some launch failed synchronously (absmax ~= 48)
    if (hipGetLastError() != hipSuccess)
        hipMemsetAsync(d_out, 0x42, (size_t)out_size * 4, stream);
}